// Round 2
// baseline (669.468 us; speedup 1.0000x reference)
//
#include <hip/hip_runtime.h>
#include <hip/hip_bf16.h>

#define EPS 1e-9f
#define LN_EPS 1e-5f

// ---------- helpers ----------
__device__ __forceinline__ float lo16(unsigned p) { return __uint_as_float(p << 16); }
__device__ __forceinline__ float hi16(unsigned p) { return __uint_as_float(p & 0xffff0000u); }
__device__ __forceinline__ unsigned f2b(float f) {
    unsigned u = __float_as_uint(f);
    return (u + 0x7fffu + ((u >> 16) & 1u)) >> 16;  // round-to-nearest-even
}
__device__ __forceinline__ float wred(float v) {
    #pragma unroll
    for (int m = 32; m >= 1; m >>= 1) v += __shfl_xor(v, m);
    return v;
}
// edge_index element i (tgt offset already applied by caller), robust to int32/int64
__device__ __forceinline__ int eidx(const int* ei, int i, int i64) {
    return i64 ? ei[2 * i] : ei[i];   // little-endian: low dword of int64
}
__device__ __forceinline__ float ldw(const float* fp, const __hip_bfloat16* hp, int i, int f32) {
    return f32 ? fp[i] : __bfloat162float(hp[i]);
}

// ---------- K0: dtype probe (1 wave). flags[0]=1 if floats are fp32; flags[1]=1 if idx int64 ----------
__global__ void probe_kernel(const unsigned* __restrict__ xb, const int* __restrict__ ei,
                             int* __restrict__ flags) {
    int lane = threadIdx.x & 63;
    unsigned d = xb[lane * 97];
    unsigned ex = (d >> 7) & 0xFFu;              // bf16-packed: low-half bf16 exponent field
    unsigned long long m1 = __ballot(ex >= 110u && ex <= 135u);
    int hi = ei[2 * lane + 1];                   // int64: odd dwords are all zero
    unsigned long long m2 = __ballot(hi == 0);
    if (lane == 0) {
        flags[0] = (__popcll(m1) > 32) ? 0 : 1;  // many bf16-exponent hits -> packed bf16
        flags[1] = (__popcll(m2) > 32) ? 1 : 0;
    }
}

// ---------- K2: per-edge softmax denominator + degree count ----------
__global__ void edge_denom_count(const int* __restrict__ ei, const float* __restrict__ ewf,
                                 const __hip_bfloat16* __restrict__ ewh,
                                 float* __restrict__ denom, int* __restrict__ count,
                                 const int* __restrict__ flags, int E) {
    int e = blockIdx.x * 256 + threadIdx.x;
    if (e >= E) return;
    int f32 = flags[0], i64 = flags[1];
    int t = eidx(ei, E + e, i64);
    float w = ldw(ewf, ewh, e, f32);
    atomicAdd(&denom[t], expf(w));
    atomicAdd(&count[t], 1);
}

// ---------- K3: single-block exclusive scan over counts -> offsets, cursor ----------
__global__ void scan_kernel(const int* __restrict__ count, int* __restrict__ offsets,
                            int* __restrict__ cursor, int N) {
    __shared__ int wsum[16];
    __shared__ int s_carry;
    int tid = threadIdx.x, lane = tid & 63, w = tid >> 6;
    if (tid == 0) s_carry = 0;
    __syncthreads();
    for (int base = 0; base < N; base += 1024) {
        int i = base + tid;
        int v = (i < N) ? count[i] : 0;
        int incl = v;
        #pragma unroll
        for (int off = 1; off < 64; off <<= 1) {
            int t = __shfl_up(incl, off);
            if (lane >= off) incl += t;
        }
        if (lane == 63) wsum[w] = incl;
        __syncthreads();
        int wpre = 0, tot = 0;
        #pragma unroll
        for (int j = 0; j < 16; ++j) { int s = wsum[j]; if (j < w) wpre += s; tot += s; }
        int excl = s_carry + wpre + incl - v;
        if (i < N) { offsets[i] = excl; cursor[i] = excl; }
        __syncthreads();
        if (tid == 0) s_carry += tot;
        __syncthreads();
    }
    if (threadIdx.x == 0) offsets[N] = s_carry;
}

// ---------- K4: scatter edges into CSR buckets with precomputed alpha ----------
__global__ void edge_scatter(const int* __restrict__ ei, const float* __restrict__ ewf,
                             const __hip_bfloat16* __restrict__ ewh,
                             const float* __restrict__ denom, int* __restrict__ cursor,
                             int* __restrict__ csr_src, float* __restrict__ csr_alpha,
                             const int* __restrict__ flags, int E) {
    int e = blockIdx.x * 256 + threadIdx.x;
    if (e >= E) return;
    int f32 = flags[0], i64 = flags[1];
    int t = eidx(ei, E + e, i64);
    int s = eidx(ei, e, i64);
    float w = ldw(ewf, ewh, e, f32);
    float al = expf(w) / denom[t];
    int pos = atomicAdd(&cursor[t], 1);
    csr_src[pos] = s;
    csr_alpha[pos] = al;
}

// ---------- K5: one wave per target node; weighted sum of x[src], proj-normalize ----------
__global__ void aggregate(const unsigned* __restrict__ xb, const float2* __restrict__ xf,
                          const int* __restrict__ offsets, const int* __restrict__ csr_src,
                          const float* __restrict__ csr_alpha, float2* __restrict__ agg,
                          const int* __restrict__ flags, int N) {
    int node = blockIdx.x * 4 + (threadIdx.x >> 6);
    if (node >= N) return;
    int lane = threadIdx.x & 63;
    int f32 = flags[0];
    float a0 = 0.f, a1 = 0.f;
    int beg = offsets[node], end = offsets[node + 1];
    if (f32) {
        for (int j = beg; j < end; ++j) {
            int s = csr_src[j];
            float al = csr_alpha[j];
            float2 v = xf[s * 64 + lane];
            a0 += al * v.x; a1 += al * v.y;
        }
    } else {
        for (int j = beg; j < end; ++j) {
            int s = csr_src[j];
            float al = csr_alpha[j];
            unsigned p = xb[s * 64 + lane];
            a0 += al * lo16(p); a1 += al * hi16(p);
        }
    }
    float ss = wred(a0 * a0 + a1 * a1);
    float inv = 1.f / (sqrtf(ss) + EPS);
    agg[node * 64 + lane] = make_float2(a0 * inv, a1 * inv);
}

// ---------- K6: fused dual matvec + combine + proj-normalize + layernorm ----------
__global__ void fused_out(const unsigned* __restrict__ xb, const float2* __restrict__ xf,
                          const float2* __restrict__ agg,
                          const unsigned* __restrict__ Wsb, const float2* __restrict__ Wsf,
                          const unsigned* __restrict__ Wnb, const float2* __restrict__ Wnf,
                          const float* __restrict__ bsf, const __hip_bfloat16* __restrict__ bsh,
                          const float* __restrict__ bnf, const __hip_bfloat16* __restrict__ bnh,
                          const float* __restrict__ gf, const __hip_bfloat16* __restrict__ gh,
                          const float* __restrict__ tf, const __hip_bfloat16* __restrict__ th,
                          unsigned* __restrict__ outb, float2* __restrict__ outf,
                          const int* __restrict__ flags, int N) {
    int node = blockIdx.x * 4 + (threadIdx.x >> 6);
    if (node >= N) return;
    int lane = threadIdx.x & 63;
    int f32 = flags[0];
    int idx = node * 64 + lane;
    float xv0, xv1;
    if (f32) { float2 t = xf[idx]; xv0 = t.x; xv1 = t.y; }
    else     { unsigned p = xb[idx]; xv0 = lo16(p); xv1 = hi16(p); }
    float2 ag = agg[idx];
    float av0 = ag.x, av1 = ag.y;
    float s0 = 0.f, s1 = 0.f, n0 = 0.f, n1 = 0.f;
    if (f32) {
        #pragma unroll 8
        for (int kl = 0; kl < 64; ++kl) {
            float xk0 = __shfl(xv0, kl), xk1 = __shfl(xv1, kl);
            float ak0 = __shfl(av0, kl), ak1 = __shfl(av1, kl);
            int k0 = 2 * kl;
            float2 ws0 = Wsf[k0 * 64 + lane], ws1 = Wsf[(k0 + 1) * 64 + lane];
            float2 wn0 = Wnf[k0 * 64 + lane], wn1 = Wnf[(k0 + 1) * 64 + lane];
            s0 += xk0 * ws0.x + xk1 * ws1.x;
            s1 += xk0 * ws0.y + xk1 * ws1.y;
            n0 += ak0 * wn0.x + ak1 * wn1.x;
            n1 += ak0 * wn0.y + ak1 * wn1.y;
        }
    } else {
        #pragma unroll 8
        for (int kl = 0; kl < 64; ++kl) {
            float xk0 = __shfl(xv0, kl), xk1 = __shfl(xv1, kl);
            float ak0 = __shfl(av0, kl), ak1 = __shfl(av1, kl);
            int k0 = 2 * kl;
            unsigned ws0 = Wsb[k0 * 64 + lane], ws1 = Wsb[(k0 + 1) * 64 + lane];
            unsigned wn0 = Wnb[k0 * 64 + lane], wn1 = Wnb[(k0 + 1) * 64 + lane];
            s0 += xk0 * lo16(ws0) + xk1 * lo16(ws1);
            s1 += xk0 * hi16(ws0) + xk1 * hi16(ws1);
            n0 += ak0 * lo16(wn0) + ak1 * lo16(wn1);
            n1 += ak0 * hi16(wn0) + ak1 * hi16(wn1);
        }
    }
    int f0 = 2 * lane, f1 = 2 * lane + 1;
    s0 += ldw(bsf, bsh, f0, f32); s1 += ldw(bsf, bsh, f1, f32);
    n0 += ldw(bnf, bnh, f0, f32); n1 += ldw(bnf, bnh, f1, f32);
    float c0 = 0.5f * (s0 + n0), c1 = 0.5f * (s1 + n1);
    float ss = wred(c0 * c0 + c1 * c1);
    float inv = 1.f / (sqrtf(ss) + EPS);
    c0 *= inv; c1 *= inv;
    float mean = wred(c0 + c1) * (1.f / 128.f);
    float d0 = c0 - mean, d1 = c1 - mean;
    float var = wred(d0 * d0 + d1 * d1) * (1.f / 128.f);
    float rstd = 1.f / sqrtf(var + LN_EPS);
    float o0 = d0 * rstd * ldw(gf, gh, f0, f32) + ldw(tf, th, f0, f32);
    float o1 = d1 * rstd * ldw(gf, gh, f1, f32) + ldw(tf, th, f1, f32);
    if (f32) outf[idx] = make_float2(o0, o1);
    else     outb[idx] = f2b(o0) | (f2b(o1) << 16);
}

extern "C" void kernel_launch(void* const* d_in, const int* in_sizes, int n_in,
                              void* d_out, int out_size, void* d_ws, size_t ws_size,
                              hipStream_t stream) {
    int N = in_sizes[0] / 128;
    int E = in_sizes[1] / 2;
    const int* ei = (const int*)d_in[1];

    char* p = (char*)d_ws;
    int* flags = (int*)p;              p += 16;
    float* denom = (float*)p;          p += (size_t)N * 4;
    int* count = (int*)p;              p += (size_t)N * 4;
    int* offsets = (int*)p;            p += (size_t)(N + 4) * 4;  // +4 keeps 16B alignment
    int* cursor = (int*)p;             p += (size_t)N * 4;
    int* csr_src = (int*)p;            p += (size_t)E * 4;
    float* csr_alpha = (float*)p;      p += (size_t)E * 4;
    float2* agg = (float2*)p;          // N*64 float2 = 25.6 MB

    // zero flags + denom + count (contiguous at start of ws)
    hipMemsetAsync(d_ws, 0, 16 + (size_t)N * 8, stream);

    int eb = (E + 255) / 256;
    int nb = (N + 3) / 4;
    probe_kernel<<<1, 64, 0, stream>>>((const unsigned*)d_in[0], ei, flags);
    edge_denom_count<<<eb, 256, 0, stream>>>(ei, (const float*)d_in[2], (const __hip_bfloat16*)d_in[2],
                                             denom, count, flags, E);
    scan_kernel<<<1, 1024, 0, stream>>>(count, offsets, cursor, N);
    edge_scatter<<<eb, 256, 0, stream>>>(ei, (const float*)d_in[2], (const __hip_bfloat16*)d_in[2],
                                         denom, cursor, csr_src, csr_alpha, flags, E);
    aggregate<<<nb, 256, 0, stream>>>((const unsigned*)d_in[0], (const float2*)d_in[0],
                                      offsets, csr_src, csr_alpha, agg, flags, N);
    fused_out<<<nb, 256, 0, stream>>>((const unsigned*)d_in[0], (const float2*)d_in[0], agg,
                                      (const unsigned*)d_in[3], (const float2*)d_in[3],
                                      (const unsigned*)d_in[5], (const float2*)d_in[5],
                                      (const float*)d_in[4], (const __hip_bfloat16*)d_in[4],
                                      (const float*)d_in[6], (const __hip_bfloat16*)d_in[6],
                                      (const float*)d_in[7], (const __hip_bfloat16*)d_in[7],
                                      (const float*)d_in[8], (const __hip_bfloat16*)d_in[8],
                                      (unsigned*)d_out, (float2*)d_out, flags, N);
}